// Round 4
// baseline (5246.308 us; speedup 1.0000x reference)
//
#include <hip/hip_runtime.h>
#include <math.h>

#define SEQ   2048
#define BATCH 128
#define HID   256
#define NCH   16   // k-chunks
#define KCH   16   // floats per chunk
#define VST   20   // chunk stride in floats (80B): 16 chunk bases -> 8 bank
                   // quads x 2 addrs = 2-way max on b128 reads (free, m136)
#define NB    4    // batch elements (independent recurrences) per block

// dst = src's value from lane (lane perm pattern) via DPP (VALU pipe, no LDS).
// 0xB1 = quad_perm [1,0,3,2] (xor1); 0x4E = quad_perm [2,3,0,1] (xor2);
// 0x124/0x128 = row_ror:4/8 within each 16-lane row. ror8 == xor8 within 16
// lanes; ror4 == xor4 after the ror8 fold (lanes l, l^8 are then bitwise
// duplicates). Numerics validated rounds 0-3 (absmax 2.98e-08 throughout).
template <int CTRL>
__device__ __forceinline__ float dpp_mov(float x) {
    return __int_as_float(__builtin_amdgcn_update_dpp(
        __float_as_int(x), __float_as_int(x), CTRL, 0xF, 0xF, false));
}

// ROUND-4 STRUCTURE: phase-shifted multi-batch blocks.
// Rounds 0-3 localized the bottleneck: ~680 cyc/step of inter-barrier latency
// (DPP-reduce dep chain -> expf -> rcp -> ds_write -> lgkm drain -> barrier ->
// ds_read latency -> first FMA) that lockstep barriers expose fully — extra
// same-phase waves don't help (round 3: stall unchanged at 2x occupancy).
// Fix: each block owns NB=4 independent recurrences (batch elements) and
// steps them back-to-back inside ONE barrier interval. Phase p's serial tail
// overlaps phases p+1..'s independent FMA streams; ONE __syncthreads per NB
// phases (4x fewer barriers); waves may drift a whole interval. W_eff VGPRs
// are shared across the 4 recurrences (same weights) — no extra pressure.
// Per-phase structure is the validated round-0 one: 512 threads, thread
// (R=tid>>4, l=tid&15) covers rows 8R+((tid&7)^j) j=0..7 x chunk [16l,16l+16),
// all-DPP reduce, threads tid / tid^8 bitwise-duplicate each row.
__global__ __launch_bounds__(512) __attribute__((amdgpu_waves_per_eu(2, 2)))
void rnn_scan_kernel(const float* __restrict__ x,        // (SEQ, BATCH)
                     const float* __restrict__ h0,       // (BATCH, HID)
                     const float* __restrict__ W_ih,     // (HID, 1)
                     const float* __restrict__ W_hh,     // (HID, HID)
                     const float* __restrict__ W_hh_b,   // (HID, HID)
                     const float* __restrict__ b_h,      // (HID,)
                     const int*   __restrict__ context,  // scalar
                     float*       __restrict__ out_hs)   // (BATCH, SEQ, HID)
{
    const int b0  = blockIdx.x * NB;
    const int tid = threadIdx.x;
    const int R   = tid >> 4;    // row-group: rows [8R, 8R+8)
    const int l   = tid & 15;    // k-chunk index
    const int l7  = tid & 7;
    const int row = 8 * R + l7;  // row this thread owns after the reduce

    __shared__ __align__(16) float v_lds[NB][2][NCH * VST];
    __shared__ float x_lds[NB][SEQ];

    for (int i = tid; i < NB * SEQ; i += 512) {
        const int p = i >> 11;          // SEQ = 2048
        const int t = i & (SEQ - 1);
        x_lds[p][t] = x[t * BATCH + (b0 + p)];
    }

    const float ctx = (float)context[0];

    // wreg[j][c] = W_eff[8R + (l7^j)][16l + 4c .. +3]  (XOR-ordered rows)
    float4 wreg[8][4];
    #pragma unroll
    for (int j = 0; j < 8; ++j) {
        const int rj = 8 * R + (l7 ^ j);
        const float* wp = W_hh   + (size_t)rj * HID + KCH * l;
        const float* bp = W_hh_b + (size_t)rj * HID + KCH * l;
        #pragma unroll
        for (int c = 0; c < 4; ++c) {
            const float4 a = *(const float4*)(wp + 4 * c);
            const float4 d = *(const float4*)(bp + 4 * c);
            wreg[j][c] = make_float4(a.x + ctx * d.x, a.y + ctx * d.y,
                                     a.z + ctx * d.z, a.w + ctx * d.w);
        }
    }

    const float winj = W_ih[row];
    const float bhj  = b_h[row];

    const int voff = VST * (row >> 4) + (row & 15);
    #pragma unroll
    for (int p = 0; p < NB; ++p)
        v_lds[p][0][voff] = 2.f * h0[(size_t)(b0 + p) * HID + row] - 1.f; // dup-safe

    float* outp0 = out_hs + (size_t)(b0 + 0) * SEQ * HID + row;
    float* outp1 = out_hs + (size_t)(b0 + 1) * SEQ * HID + row;
    float* outp2 = out_hs + (size_t)(b0 + 2) * SEQ * HID + row;
    float* outp3 = out_hs + (size_t)(b0 + 3) * SEQ * HID + row;

    __syncthreads();  // v[*][0] + x_lds ready

    // One recurrence step for one batch element. vbr/vbw are the parity
    // buffers; xrow = x_lds[p]; outp = this batch's hs base.
    auto phase = [&](int t, const float* __restrict__ vbr,
                     float* __restrict__ vbw,
                     const float* __restrict__ xrow,
                     float* __restrict__ outp) {
        const float4* vr = (const float4*)(vbr + VST * l);  // 80B-stride
        float q[8] = {0.f, 0.f, 0.f, 0.f, 0.f, 0.f, 0.f, 0.f};
        #pragma unroll
        for (int c = 0; c < 4; ++c) {
            const float4 v4 = vr[c];
            #pragma unroll
            for (int j = 0; j < 8; ++j) {
                const float4 w = wreg[j][c];
                q[j] += w.x * v4.x;
                q[j] += w.y * v4.y;
                q[j] += w.z * v4.z;
                q[j] += w.w * v4.w;
            }
        }
        // Fold l <-> l^8 (chunks), then XOR transpose via quad_perm + ror4.
        #pragma unroll
        for (int j = 0; j < 8; ++j) q[j] += dpp_mov<0x128>(q[j]);
        q[0] += dpp_mov<0xB1>(q[1]);
        q[2] += dpp_mov<0xB1>(q[3]);
        q[4] += dpp_mov<0xB1>(q[5]);
        q[6] += dpp_mov<0xB1>(q[7]);
        q[0] += dpp_mov<0x4E>(q[2]);
        q[4] += dpp_mov<0x4E>(q[6]);
        q[0] += dpp_mov<0x124>(q[4]);
        // q[0] = full dot for row 8R + l7 (dup in tid and tid^8)

        const float pre = q[0] + bhj + xrow[t] * winj;
        const float h = 1.f / (1.f + __expf(-pre));
        vbw[voff] = 2.f * h - 1.f;                // dup write, same value
        if ((tid & 8) == 0)
            outp[(size_t)t * HID] = h;            // 32 lanes/wave, 64B runs
    };

    for (int t = 0; t < SEQ; t += 2) {
        // parity 0: read buf0, write buf1 — all NB phases, then ONE barrier
        phase(t, v_lds[0][0], v_lds[0][1], x_lds[0], outp0);
        phase(t, v_lds[1][0], v_lds[1][1], x_lds[1], outp1);
        phase(t, v_lds[2][0], v_lds[2][1], x_lds[2], outp2);
        phase(t, v_lds[3][0], v_lds[3][1], x_lds[3], outp3);
        __syncthreads();
        // parity 1: read buf1, write buf0
        phase(t + 1, v_lds[0][1], v_lds[0][0], x_lds[0], outp0);
        phase(t + 1, v_lds[1][1], v_lds[1][0], x_lds[1], outp1);
        phase(t + 1, v_lds[2][1], v_lds[2][0], x_lds[2], outp2);
        phase(t + 1, v_lds[3][1], v_lds[3][0], x_lds[3], outp3);
        __syncthreads();
    }
}

// y[r] = dot(hs[r,:], W[0,:]) + bias[0]. 16 lanes/row, 4 rows/wave; each lane
// covers 16 floats; shfl-xor tree over 16 lanes. (Validated round 0.)
__global__ __launch_bounds__(256, 4)
void head_kernel(const float* __restrict__ hs,   // (BATCH*SEQ, HID)
                 const float* __restrict__ W,    // (OUTD, HID)
                 const float* __restrict__ bias, // (OUTD,)
                 float*       __restrict__ y)    // (BATCH*SEQ,)
{
    const int tid  = threadIdx.x;
    const int lane = tid & 63;
    const int sub  = lane & 15;
    const int rsub = lane >> 4;

    float4 w0[4];
    #pragma unroll
    for (int u = 0; u < 4; ++u)
        w0[u] = *(const float4*)(W + 4 * (16 * u + sub));
    const float b0 = bias[0];

    const int gwave = (blockIdx.x * blockDim.x + tid) >> 6;
    const int nw    = (gridDim.x * blockDim.x) >> 6;
    const int nq    = (BATCH * SEQ) >> 2;

    for (int q = gwave; q < nq; q += nw) {
        const int rrow = q * 4 + rsub;
        const float* rp = hs + (size_t)rrow * HID;
        float s = 0.f;
        #pragma unroll
        for (int u = 0; u < 4; ++u) {
            const float4 hv = *(const float4*)(rp + 4 * (16 * u + sub));
            s += hv.x * w0[u].x + hv.y * w0[u].y +
                 hv.z * w0[u].z + hv.w * w0[u].w;
        }
        s += __shfl_xor(s, 1, 64);
        s += __shfl_xor(s, 2, 64);
        s += __shfl_xor(s, 4, 64);
        s += __shfl_xor(s, 8, 64);
        if (sub == 0) y[rrow] = s + b0;
    }
}

extern "C" void kernel_launch(void* const* d_in, const int* in_sizes, int n_in,
                              void* d_out, int out_size, void* d_ws, size_t ws_size,
                              hipStream_t stream) {
    const float* x      = (const float*)d_in[0];
    const float* h0     = (const float*)d_in[1];
    const float* W_ih   = (const float*)d_in[2];
    const float* W_hh   = (const float*)d_in[3];
    const float* W_hh_b = (const float*)d_in[4];
    const float* b_h    = (const float*)d_in[5];
    const float* W      = (const float*)d_in[6];
    const float* bias   = (const float*)d_in[7];
    const int*   ctx    = (const int*)d_in[8];

    float* y  = (float*)d_out;                // (BATCH*SEQ,) = y[:,:,0]
    float* hs = y + (size_t)BATCH * SEQ;      // (BATCH, SEQ, HID) = out

    rnn_scan_kernel<<<BATCH / NB, 512, 0, stream>>>(x, h0, W_ih, W_hh, W_hh_b,
                                                    b_h, ctx, hs);
    head_kernel<<<2048, 256, 0, stream>>>(hs, W, bias, y);
}

// Round 5
// 1470.492 us; speedup vs baseline: 3.5677x; 3.5677x over previous
//
#include <hip/hip_runtime.h>
#include <math.h>

#define SEQ   2048
#define BATCH 128
#define HID   256
#define NCH   16   // k-chunks
#define KCH   16   // floats per chunk
#define VST   20   // chunk stride in floats (80B): 16 chunk bases -> 8 bank
                   // quads x 2 addrs = 2-way max on b128 reads (free, m136)

// dst = src's value from lane (lane perm pattern) via DPP (VALU pipe, no LDS).
// 0xB1 = quad_perm [1,0,3,2] (xor1); 0x4E = quad_perm [2,3,0,1] (xor2);
// 0x124/0x128 = row_ror:4/8 within each 16-lane row. ror8 == xor8 within 16
// lanes; ror4 == xor4 after the ror8 fold (lanes l, l^8 are then bitwise
// duplicates). Numerics validated rounds 0-4 (absmax 2.98e-08 throughout).
template <int CTRL>
__device__ __forceinline__ float dpp_mov(float x) {
    return __int_as_float(__builtin_amdgcn_update_dpp(
        __float_as_int(x), __float_as_int(x), CTRL, 0xF, 0xF, false));
}

// ROUND-5: the active CUs are VALU-ISSUE-SATURATED (R4: 4 independent
// phases back-to-back showed ZERO overlap, per-phase time == R0 per-step
// time; VALUBusy normalized to active CUs ~= 100-105% in R0/R3/R4).
// Time == VALU instruction count / issue rate; there is no hidable stall.
// Measured ~366 instr/thread/step vs ~180 in the source. Smoking gun:
// VGPR_Count=108 while wreg alone is 128 floats (R3: count=64 == its wreg
// exactly) -> the compiler homed wreg in AGPRs (spill-to-AGPR path) and
// pays an extra access per use, ~+128 instr/thread/step == the whole gap.
// Root cause: __launch_bounds__(512) without min-waves let the allocator
// target a ~128-VGPR occupancy cap; amdgpu_waves_per_eu(2,2) didn't raise
// it. Fix: __launch_bounds__(512, 2) — declared 2 waves/EU -> ~256-VGPR
// budget -> wreg (128) + working set (~60) fit in arch VGPRs.
// Also: sigmoid via v_rcp_f32 (__builtin_amdgcn_rcpf) instead of the IEEE
// division sequence (~10 VALU saved; doubles as a numerics probe for a
// potential future bf16-split MFMA path).
//
// Structure = validated round-0: one block (512 threads, 8 waves) per batch
// element; thread (R=tid>>4, l=tid&15) owns k-chunk [16l,16l+16), rows
// 8R+((tid&7)^j) j=0..7; all-DPP reduce; threads tid / tid^8 duplicate the
// same row bitwise-identically; v=2h-1 double-buffered in LDS, one
// __syncthreads per step, K-loop unrolled x2 for static buffer pointers.
__global__ __launch_bounds__(512, 2)
void rnn_scan_kernel(const float* __restrict__ x,        // (SEQ, BATCH)
                     const float* __restrict__ h0,       // (BATCH, HID)
                     const float* __restrict__ W_ih,     // (HID, 1)
                     const float* __restrict__ W_hh,     // (HID, HID)
                     const float* __restrict__ W_hh_b,   // (HID, HID)
                     const float* __restrict__ b_h,      // (HID,)
                     const int*   __restrict__ context,  // scalar
                     float*       __restrict__ out_hs)   // (BATCH, SEQ, HID)
{
    const int b   = blockIdx.x;
    const int tid = threadIdx.x;
    const int R   = tid >> 4;    // row-group: rows [8R, 8R+8)
    const int l   = tid & 15;    // k-chunk index
    const int l7  = tid & 7;
    const int row = 8 * R + l7;  // row this thread owns after the reduce

    __shared__ __align__(16) float v_lds[2][NCH * VST];
    __shared__ float x_lds[SEQ];

    for (int t = tid; t < SEQ; t += 512)
        x_lds[t] = x[t * BATCH + b];

    const float ctx = (float)context[0];

    // wreg[j][c] = W_eff[8R + (l7^j)][16l + 4c .. +3]  (XOR-ordered rows)
    float4 wreg[8][4];
    #pragma unroll
    for (int j = 0; j < 8; ++j) {
        const int rj = 8 * R + (l7 ^ j);
        const float* wp = W_hh   + (size_t)rj * HID + KCH * l;
        const float* bp = W_hh_b + (size_t)rj * HID + KCH * l;
        #pragma unroll
        for (int c = 0; c < 4; ++c) {
            const float4 a = *(const float4*)(wp + 4 * c);
            const float4 d = *(const float4*)(bp + 4 * c);
            wreg[j][c] = make_float4(a.x + ctx * d.x, a.y + ctx * d.y,
                                     a.z + ctx * d.z, a.w + ctx * d.w);
        }
    }

    const float winj = W_ih[row];
    const float bhj  = b_h[row];

    const int voff = VST * (row >> 4) + (row & 15);
    v_lds[0][voff] = 2.f * h0[(size_t)b * HID + row] - 1.f;  // dup-safe

    float* outp = out_hs + (size_t)b * SEQ * HID + row;

    const float4* vr0 = (const float4*)(v_lds[0] + VST * l);  // 80B-stride
    const float4* vr1 = (const float4*)(v_lds[1] + VST * l);

    __syncthreads();  // v[0] + x_lds ready

    auto step = [&](int t, const float4* __restrict__ vr, float* __restrict__ vw) {
        float q[8] = {0.f, 0.f, 0.f, 0.f, 0.f, 0.f, 0.f, 0.f};
        #pragma unroll
        for (int c = 0; c < 4; ++c) {
            const float4 v4 = vr[c];
            #pragma unroll
            for (int j = 0; j < 8; ++j) {
                const float4 w = wreg[j][c];
                q[j] += w.x * v4.x;
                q[j] += w.y * v4.y;
                q[j] += w.z * v4.z;
                q[j] += w.w * v4.w;
            }
        }
        // Fold l <-> l^8: same rows, complementary k-halves.
        #pragma unroll
        for (int j = 0; j < 8; ++j) q[j] += dpp_mov<0x128>(q[j]);
        // XOR transpose-reduce, small masks first (all DPP, no LDS).
        q[0] += dpp_mov<0xB1>(q[1]);
        q[2] += dpp_mov<0xB1>(q[3]);
        q[4] += dpp_mov<0xB1>(q[5]);
        q[6] += dpp_mov<0xB1>(q[7]);
        q[0] += dpp_mov<0x4E>(q[2]);
        q[4] += dpp_mov<0x4E>(q[6]);
        q[0] += dpp_mov<0x124>(q[4]);
        // q[0] = full dot for row 8R + l7 (dup in tid and tid^8)

        const float pre = q[0] + bhj + x_lds[t] * winj;
        // sigmoid via v_exp + v_rcp (no IEEE div sequence): ~1e-7 rel error,
        // contracted by the sigmoid recurrence (absmax probe for bf16 path).
        const float h = __builtin_amdgcn_rcpf(1.f + __expf(-pre));
        vw[voff] = 2.f * h - 1.f;                 // dup write, same value
        if ((tid & 8) == 0)
            outp[(size_t)t * HID] = h;            // 32 lanes/wave, 64B runs
        __syncthreads();  // v for t+1 ready; buffer t fully read before reuse
    };

    for (int t = 0; t < SEQ; t += 2) {
        step(t,     vr0, v_lds[1]);
        step(t + 1, vr1, v_lds[0]);
    }
}

// y[r] = dot(hs[r,:], W[0,:]) + bias[0]. 16 lanes/row, 4 rows/wave; each lane
// covers 16 floats; shfl-xor tree over 16 lanes. (Validated round 0.)
__global__ __launch_bounds__(256, 4)
void head_kernel(const float* __restrict__ hs,   // (BATCH*SEQ, HID)
                 const float* __restrict__ W,    // (OUTD, HID)
                 const float* __restrict__ bias, // (OUTD,)
                 float*       __restrict__ y)    // (BATCH*SEQ,)
{
    const int tid  = threadIdx.x;
    const int lane = tid & 63;
    const int sub  = lane & 15;
    const int rsub = lane >> 4;

    float4 w0[4];
    #pragma unroll
    for (int u = 0; u < 4; ++u)
        w0[u] = *(const float4*)(W + 4 * (16 * u + sub));
    const float b0 = bias[0];

    const int gwave = (blockIdx.x * blockDim.x + tid) >> 6;
    const int nw    = (gridDim.x * blockDim.x) >> 6;
    const int nq    = (BATCH * SEQ) >> 2;

    for (int q = gwave; q < nq; q += nw) {
        const int rrow = q * 4 + rsub;
        const float* rp = hs + (size_t)rrow * HID;
        float s = 0.f;
        #pragma unroll
        for (int u = 0; u < 4; ++u) {
            const float4 hv = *(const float4*)(rp + 4 * (16 * u + sub));
            s += hv.x * w0[u].x + hv.y * w0[u].y +
                 hv.z * w0[u].z + hv.w * w0[u].w;
        }
        s += __shfl_xor(s, 1, 64);
        s += __shfl_xor(s, 2, 64);
        s += __shfl_xor(s, 4, 64);
        s += __shfl_xor(s, 8, 64);
        if (sub == 0) y[rrow] = s + b0;
    }
}

extern "C" void kernel_launch(void* const* d_in, const int* in_sizes, int n_in,
                              void* d_out, int out_size, void* d_ws, size_t ws_size,
                              hipStream_t stream) {
    const float* x      = (const float*)d_in[0];
    const float* h0     = (const float*)d_in[1];
    const float* W_ih   = (const float*)d_in[2];
    const float* W_hh   = (const float*)d_in[3];
    const float* W_hh_b = (const float*)d_in[4];
    const float* b_h    = (const float*)d_in[5];
    const float* W      = (const float*)d_in[6];
    const float* bias   = (const float*)d_in[7];
    const int*   ctx    = (const int*)d_in[8];

    float* y  = (float*)d_out;                // (BATCH*SEQ,) = y[:,:,0]
    float* hs = y + (size_t)BATCH * SEQ;      // (BATCH, SEQ, HID) = out

    rnn_scan_kernel<<<BATCH, 512, 0, stream>>>(x, h0, W_ih, W_hh, W_hh_b,
                                               b_h, ctx, hs);
    head_kernel<<<2048, 256, 0, stream>>>(hs, W, bias, y);
}

// Round 6
// 1403.518 us; speedup vs baseline: 3.7380x; 1.0477x over previous
//
#include <hip/hip_runtime.h>
#include <math.h>

#define SEQ   2048
#define BATCH 128
#define HID   256
#define NCH   16   // k-chunks
#define KCH   16   // floats per chunk
#define VST   20   // chunk stride in floats (80B): 16 chunk bases -> 8 bank
                   // quads x 2 addrs = 2-way max on b128 reads (free, m136)

// dst = src's value from lane (lane perm pattern) via DPP (VALU pipe, no LDS).
// 0xB1 = quad_perm [1,0,3,2] (xor1); 0x4E = quad_perm [2,3,0,1] (xor2);
// 0x124/0x128 = row_ror:4/8 within each 16-lane row. ror8 == xor8 within 16
// lanes; ror4 == xor4 after the ror8 fold (lanes l, l^8 are then bitwise
// duplicates). Numerics validated rounds 0-5 (absmax 2.98e-08 with this tail).
template <int CTRL>
__device__ __forceinline__ float dpp_mov(float x) {
    return __int_as_float(__builtin_amdgcn_update_dpp(
        __float_as_int(x), __float_as_int(x), CTRL, 0xF, 0xF, false));
}

// ROUND-6. Model after 5 A/B rounds: step(1464cy) = ~700 issue + ~760
// distributed serial exposure (read-lat, burst skew, DPP hazards, exp/div,
// write+drain+barrier). No single in-loop rock; drift impossible (barrier
// lockstep; registers forbid multi-batch interleave, R4; occupancy doesn't
// help, R3; vmcnt drain & store-ack are non-issues, R1/R2; AGPR residence is
// full-rate, R5). The one clearly-positive lever left: every round shows
// total-minus-scan ~= 190-200us while the head kernel's HBM work is ~50us
// -> ~140us of two-kernel launch/gap overhead. Fix: FUSE THE HEAD AS AN
// EPILOGUE (per-step y-fusion failed in R1/R2 because it sat on the step's
// serial critical path; a post-loop epilogue has no such path).
//
// Structure = validated round-0 (best measured, 1248us dispatch): one block
// (512 threads, 8 waves, 2 waves/SIMD) per batch element; thread
// (R=tid>>4, l=tid&15) owns k-chunk [16l,16l+16), rows 8R+((tid&7)^j)
// j=0..7 (128 weight fp32, AGPR-resident, full-rate); all-DPP reduce;
// threads tid / tid^8 duplicate each row bitwise-identically; v = 2h-1
// double-buffered in LDS; ONE __syncthreads/step; K-loop unrolled x2.
__global__ __launch_bounds__(512) __attribute__((amdgpu_waves_per_eu(2, 2)))
void rnn_scan_kernel(const float* __restrict__ x,        // (SEQ, BATCH)
                     const float* __restrict__ h0,       // (BATCH, HID)
                     const float* __restrict__ W_ih,     // (HID, 1)
                     const float* __restrict__ W_hh,     // (HID, HID)
                     const float* __restrict__ W_hh_b,   // (HID, HID)
                     const float* __restrict__ b_h,      // (HID,)
                     const int*   __restrict__ context,  // scalar
                     const float* __restrict__ Wout,     // (OUT, HID), row 0
                     const float* __restrict__ bias,     // (OUT,), [0]
                     float*       __restrict__ out_hs,   // (BATCH, SEQ, HID)
                     float*       __restrict__ out_y)    // (BATCH, SEQ)
{
    const int b   = blockIdx.x;
    const int tid = threadIdx.x;
    const int R   = tid >> 4;    // row-group: rows [8R, 8R+8)
    const int l   = tid & 15;    // k-chunk index
    const int l7  = tid & 7;
    const int row = 8 * R + l7;  // row this thread owns after the reduce

    __shared__ __align__(16) float v_lds[2][NCH * VST];
    __shared__ float x_lds[SEQ];

    for (int t = tid; t < SEQ; t += 512)
        x_lds[t] = x[t * BATCH + b];

    const float ctx = (float)context[0];

    // wreg[j][c] = W_eff[8R + (l7^j)][16l + 4c .. +3]  (XOR-ordered rows)
    float4 wreg[8][4];
    #pragma unroll
    for (int j = 0; j < 8; ++j) {
        const int rj = 8 * R + (l7 ^ j);
        const float* wp = W_hh   + (size_t)rj * HID + KCH * l;
        const float* bp = W_hh_b + (size_t)rj * HID + KCH * l;
        #pragma unroll
        for (int c = 0; c < 4; ++c) {
            const float4 a = *(const float4*)(wp + 4 * c);
            const float4 d = *(const float4*)(bp + 4 * c);
            wreg[j][c] = make_float4(a.x + ctx * d.x, a.y + ctx * d.y,
                                     a.z + ctx * d.z, a.w + ctx * d.w);
        }
    }

    const float winj = W_ih[row];
    const float bhj  = b_h[row];

    const int voff = VST * (row >> 4) + (row & 15);
    v_lds[0][voff] = 2.f * h0[(size_t)b * HID + row] - 1.f;  // dup-safe

    float* outp = out_hs + (size_t)b * SEQ * HID + row;

    const float4* vr0 = (const float4*)(v_lds[0] + VST * l);  // 80B-stride
    const float4* vr1 = (const float4*)(v_lds[1] + VST * l);

    __syncthreads();  // v[0] + x_lds ready

    auto step = [&](int t, const float4* __restrict__ vr, float* __restrict__ vw) {
        const float xt = x_lds[t];   // hoisted: issue with the v-read burst
        float q[8] = {0.f, 0.f, 0.f, 0.f, 0.f, 0.f, 0.f, 0.f};
        #pragma unroll
        for (int c = 0; c < 4; ++c) {
            const float4 v4 = vr[c];
            #pragma unroll
            for (int j = 0; j < 8; ++j) {
                const float4 w = wreg[j][c];
                q[j] += w.x * v4.x;
                q[j] += w.y * v4.y;
                q[j] += w.z * v4.z;
                q[j] += w.w * v4.w;
            }
        }
        // Fold l <-> l^8: same rows, complementary k-halves.
        #pragma unroll
        for (int j = 0; j < 8; ++j) q[j] += dpp_mov<0x128>(q[j]);
        // XOR transpose-reduce, small masks first (all DPP, no LDS).
        q[0] += dpp_mov<0xB1>(q[1]);
        q[2] += dpp_mov<0xB1>(q[3]);
        q[4] += dpp_mov<0xB1>(q[5]);
        q[6] += dpp_mov<0xB1>(q[7]);
        q[0] += dpp_mov<0x4E>(q[2]);
        q[4] += dpp_mov<0x4E>(q[6]);
        q[0] += dpp_mov<0x124>(q[4]);
        // q[0] = full dot for row 8R + l7 (dup in tid and tid^8)

        const float pre = q[0] + bhj + xt * winj;
        const float h = 1.f / (1.f + __expf(-pre));   // IEEE div: absmax 3e-8
        vw[voff] = 2.f * h - 1.f;                 // dup write, same value
        if ((tid & 8) == 0)
            outp[(size_t)t * HID] = h;            // 32 lanes/wave, 64B runs
        __syncthreads();  // v for t+1 ready; buffer t fully read before reuse
    };

    for (int t = 0; t < SEQ; t += 2) {
        step(t,     vr0, v_lds[1]);
        step(t + 1, vr1, v_lds[0]);
    }

    // ---- fused head epilogue: y[b,t] = dot(hs[b,t,:], Wout[0,:]) + bias[0].
    // Our block wrote all of hs[b]; fence makes every thread's stores visible,
    // barrier makes every thread's fence done. 16 lanes/row x 16 floats/lane,
    // 32 rows in flight, shfl-xor tree over 16 lanes (validated head inner).
    __threadfence();
    __syncthreads();

    {
        const int sub  = tid & 15;
        const int rsub = tid >> 4;           // 0..31
        float4 w0[4];
        #pragma unroll
        for (int u = 0; u < 4; ++u)
            w0[u] = *(const float4*)(Wout + 4 * (16 * u + sub));
        const float b0 = bias[0];
        const float* hsb = out_hs + (size_t)b * SEQ * HID;
        float* yp = out_y + (size_t)b * SEQ;

        for (int r0 = 0; r0 < SEQ; r0 += 32) {
            const int t = r0 + rsub;
            const float* rp = hsb + (size_t)t * HID;
            float s = 0.f;
            #pragma unroll
            for (int u = 0; u < 4; ++u) {
                const float4 hv = *(const float4*)(rp + 4 * (16 * u + sub));
                s += hv.x * w0[u].x + hv.y * w0[u].y +
                     hv.z * w0[u].z + hv.w * w0[u].w;
            }
            s += __shfl_xor(s, 1, 64);
            s += __shfl_xor(s, 2, 64);
            s += __shfl_xor(s, 4, 64);
            s += __shfl_xor(s, 8, 64);
            if (sub == 0) yp[t] = s + b0;
        }
    }
}

extern "C" void kernel_launch(void* const* d_in, const int* in_sizes, int n_in,
                              void* d_out, int out_size, void* d_ws, size_t ws_size,
                              hipStream_t stream) {
    const float* x      = (const float*)d_in[0];
    const float* h0     = (const float*)d_in[1];
    const float* W_ih   = (const float*)d_in[2];
    const float* W_hh   = (const float*)d_in[3];
    const float* W_hh_b = (const float*)d_in[4];
    const float* b_h    = (const float*)d_in[5];
    const float* W      = (const float*)d_in[6];
    const float* bias   = (const float*)d_in[7];
    const int*   ctx    = (const int*)d_in[8];

    float* y  = (float*)d_out;                // (BATCH*SEQ,) = y[:,:,0]
    float* hs = y + (size_t)BATCH * SEQ;      // (BATCH, SEQ, HID) = out

    rnn_scan_kernel<<<BATCH, 512, 0, stream>>>(x, h0, W_ih, W_hh, W_hh_b,
                                               b_h, ctx, W, bias, hs, y);
}